// Round 1
// baseline (457.883 us; speedup 1.0000x reference)
//
#include <hip/hip_runtime.h>
#include <hip/hip_bf16.h>
#include <math.h>

// Shapes (fixed by the problem)
#define BATCH 8
#define CDIM 16
#define RDIM 16
#define MDIM 512
#define NDIM 512

// Workspace layout (in floats)
#define WS_T       0          // t[b][k][l]  8*4*32 = 1024
#define WS_DE      1024       // d,e per (b,c): [8][16][2] = 256
#define WS_SCAL    1280       // alpha_r, alpha_i, CC
#define WS_STATS   1296       // [8][2] mu, rstd
#define WS_MIS     2048       // mi_s [8][16][512][2] = 131072
#define WS_MJS     133120     // mj_s [8][16][512][2] = 131072
#define WS_MOD     264192     // mod / wd0 in-place [8][512][512][2] = 4194304
#define WS_G1      4458496    // G1 [8][512][512][2] = 4194304
#define WS_PART    8652800    // partials [8][64][2] = 1024

// ---------------------------------------------------------------------------
// k_prep: t = einsum('bc,kcl->bkl'); d,e per (b,c); alpha/CC scalars
// ---------------------------------------------------------------------------
__global__ void k_prep(const float* __restrict__ x, const float* __restrict__ mt,
                       const float* __restrict__ inv, const float* __restrict__ td,
                       const float* __restrict__ rd, float* __restrict__ ws) {
    float* tbuf = ws + WS_T;
    float* de   = ws + WS_DE;
    float* scal = ws + WS_SCAL;
    int tid = threadIdx.x; // 256 threads
    for (int i = tid; i < 1024; i += 256) {
        int b = i >> 7;          // 128 per b (4*32)
        int k = (i >> 5) & 3;
        int l = i & 31;
        float s = 0.f;
        for (int c = 0; c < 16; c++) s += x[b * 16 + c] * mt[(k * 16 + c) * 32 + l];
        tbuf[i] = s;
    }
    __syncthreads();
    if (tid < 128) {
        int b = tid >> 4, c = tid & 15;
        float i0 = inv[2 * c], i1 = inv[2 * c + 1];
        float z0 = tbuf[(b * 4 + 1) * 32 + 2 * c], z1 = tbuf[(b * 4 + 1) * 32 + 2 * c + 1];
        de[tid * 2]     = i0 * z0 + i1 * z1;   // d
        de[tid * 2 + 1] = i0 * z1 - i1 * z0;   // e
    }
    if (tid == 0) {
        float S0 = 0.f, S1 = 0.f, CCv = 0.f;
        for (int c = 0; c < 16; c++) {
            float r0 = rd[2 * c], r1 = rd[2 * c + 1];
            float t0 = td[2 * c], t1 = td[2 * c + 1];
            S0 += r0; S1 += r1;
            CCv += t1 * r1 - t0 * r0;
        }
        scal[0] = -S0;   // alpha_r
        scal[1] = -S1;   // alpha_i
        scal[2] = CCv;   // CC
    }
}

// ---------------------------------------------------------------------------
// k_mi: mi_s[b,r,m] = sum_c W[b,c] * (mod_i[c,r,m] + t0[b,c])
// ---------------------------------------------------------------------------
__global__ void k_mi(const float* __restrict__ mod_i, float* __restrict__ ws) {
    const float* tbuf = ws + WS_T;
    const float* de   = ws + WS_DE;
    float* mi_s       = ws + WS_MIS;
    int id = blockIdx.x * 256 + threadIdx.x;  // 65536 total
    int b  = id >> 13;
    int rm = id & 8191;
    int r  = rm >> 9, m = rm & 511;
    float acc0 = 0.f, acc1 = 0.f;
    for (int c = 0; c < 16; c++) {
        const float* p = mod_i + (((size_t)(c * 16 + r) * 512) + m) * 2;
        float t00 = tbuf[(b * 4 + 0) * 32 + 2 * c];
        float t01 = tbuf[(b * 4 + 0) * 32 + 2 * c + 1];
        float d = de[(b * 16 + c) * 2], e = de[(b * 16 + c) * 2 + 1];
        float A0 = p[0] + t00, A1 = p[1] + t01;
        acc0 += d * A0 - e * A1;
        acc1 += e * A0 + d * A1;
    }
    float* dst = mi_s + ((size_t)b * 8192 + rm) * 2;
    dst[0] = acc0; dst[1] = acc1;
}

// ---------------------------------------------------------------------------
// k_mj: rotate then "division inversion", sum over c
// ---------------------------------------------------------------------------
__global__ void k_mj(const float* __restrict__ mod_j, const float* __restrict__ inv,
                     float* __restrict__ ws) {
    const float* tbuf = ws + WS_T;
    float* mj_s       = ws + WS_MJS;
    int id = blockIdx.x * 256 + threadIdx.x;
    int b  = id >> 13;
    int rn = id & 8191;
    int r  = rn >> 9, n = rn & 511;
    float acc0 = 0.f, acc1 = 0.f;
    for (int c = 0; c < 16; c++) {
        const float* p = mod_j + (((size_t)(c * 16 + r) * 512) + n) * 2;
        float t20 = tbuf[(b * 4 + 2) * 32 + 2 * c];
        float t21 = tbuf[(b * 4 + 2) * 32 + 2 * c + 1];
        float z0  = tbuf[(b * 4 + 3) * 32 + 2 * c];
        float z1  = tbuf[(b * 4 + 3) * 32 + 2 * c + 1];
        float A0 = p[0] + t20, A1 = p[1] + t21;
        float w0 = -z0 * A0 + z1 * A1;
        float w1 =  z1 * A0 + z0 * A1;
        float i0 = inv[2 * c], i1 = inv[2 * c + 1];
        float den = w0 * w0 + w1 * w1;
        acc0 += (i0 * w0 + i1 * w1) / den;
        acc1 += (i0 * w1 - i1 * w0) / den;
    }
    float* dst = mj_s + ((size_t)b * 8192 + rn) * 2;
    dst[0] = acc0; dst[1] = acc1;
}

// ---------------------------------------------------------------------------
// k_mod: mod[b,m,n] = sum_r mi_s[b,r,m] (*) mj_s[b,r,n]  (complex, rank 16)
//        + per-block partial sums of mod_r and mod_r^2
// ---------------------------------------------------------------------------
__global__ __launch_bounds__(256) void k_mod(float* __restrict__ ws) {
    const float* mi_s = ws + WS_MIS;
    const float* mj_s = ws + WS_MJS;
    float* modp       = ws + WS_MOD;
    float* partials   = ws + WS_PART;
    int nt = blockIdx.x, mt = blockIdx.y, b = blockIdx.z;
    __shared__ float As[16][128];
    __shared__ float Bs[16][128];
    __shared__ float red[512];
    int tid = threadIdx.x, tx = tid & 15, ty = tid >> 4;
    const float* Ab = mi_s + (size_t)b * 16384;
    const float* Bb = mj_s + (size_t)b * 16384;
    int m0 = mt * 64, n0 = nt * 64;
    for (int i = 0; i < 4; i++) {
        int flat = tid + i * 256;
        int col = flat & 63, r = flat >> 6;
        const float2 sa = *(const float2*)(Ab + ((size_t)r * 512 + m0 + col) * 2);
        As[r][col * 2] = sa.x; As[r][col * 2 + 1] = sa.y;
        const float2 sb = *(const float2*)(Bb + ((size_t)r * 512 + n0 + col) * 2);
        Bs[r][col * 2] = sb.x; Bs[r][col * 2 + 1] = sb.y;
    }
    __syncthreads();
    float cr[4][4] = {}, ci[4][4] = {};
    for (int r = 0; r < 16; r++) {
        float ar[4], ai[4], br[4], bi[4];
        for (int i = 0; i < 4; i++) { ar[i] = As[r][(ty * 4 + i) * 2]; ai[i] = As[r][(ty * 4 + i) * 2 + 1]; }
        for (int j = 0; j < 4; j++) { br[j] = Bs[r][(tx * 4 + j) * 2]; bi[j] = Bs[r][(tx * 4 + j) * 2 + 1]; }
        for (int i = 0; i < 4; i++)
            for (int j = 0; j < 4; j++) {
                cr[i][j] += ar[i] * br[j] - ai[i] * bi[j];
                ci[i][j] += ar[i] * bi[j] + ai[i] * br[j];
            }
    }
    float s1 = 0.f, s2 = 0.f;
    float* mb = modp + (size_t)b * 524288;
    for (int i = 0; i < 4; i++) {
        float* dst = mb + ((size_t)(m0 + ty * 4 + i) * 512 + n0 + tx * 4) * 2;
        for (int j = 0; j < 4; j++) {
            dst[j * 2] = cr[i][j]; dst[j * 2 + 1] = ci[i][j];
            s1 += cr[i][j]; s2 += cr[i][j] * cr[i][j];
        }
    }
    red[tid] = s1; red[256 + tid] = s2;
    __syncthreads();
    for (int s = 128; s > 0; s >>= 1) {
        if (tid < s) { red[tid] += red[tid + s]; red[256 + tid] += red[256 + tid + s]; }
        __syncthreads();
    }
    if (tid == 0) {
        float* dst = partials + ((size_t)b * 64 + mt * 8 + nt) * 2;
        dst[0] = red[0]; dst[1] = red[256];
    }
}

// ---------------------------------------------------------------------------
// k_stats: reduce partials -> mu, 1/std (ddof=1) per batch
// ---------------------------------------------------------------------------
__global__ void k_stats(float* __restrict__ ws) {
    const float* partials = ws + WS_PART;
    float* stats          = ws + WS_STATS;
    __shared__ float s1[512], s2[512];
    int tid = threadIdx.x; // 512
    int b = tid >> 6, i = tid & 63;
    s1[tid] = partials[(b * 64 + i) * 2];
    s2[tid] = partials[(b * 64 + i) * 2 + 1];
    __syncthreads();
    for (int s = 32; s > 0; s >>= 1) {
        if (i < s) { s1[tid] += s1[tid + s]; s2[tid] += s2[tid + s]; }
        __syncthreads();
    }
    if (i == 0) {
        double MN = 262144.0;
        double mu = (double)s1[tid] / MN;
        double var = ((double)s2[tid] - MN * mu * mu) / (MN - 1.0);
        if (var < 1e-30) var = 1e-30;
        stats[b * 2] = (float)mu;
        stats[b * 2 + 1] = (float)(1.0 / sqrt(var));
    }
}

// ---------------------------------------------------------------------------
// k_wd0: in-place  wd0 = base .* (1 + [normalize(mod_r), mod_i])
// ---------------------------------------------------------------------------
__global__ void k_wd0(const float* __restrict__ base, float* __restrict__ ws) {
    const float* stats = ws + WS_STATS;
    float* modp        = ws + WS_MOD;
    int e = blockIdx.x * 256 + threadIdx.x;   // 2,097,152 total
    int b = e >> 18;
    int rem = e & 262143;
    float mu = stats[b * 2], rstd = stats[b * 2 + 1];
    float2 mv = *(float2*)(modp + (size_t)e * 2);
    float2 bs = *(const float2*)(base + (size_t)rem * 2);
    float wr = bs.x * (1.f + (mv.x - mu) * rstd);
    float wi = bs.y * (1.f + mv.y);
    float2* dst = (float2*)(modp + (size_t)e * 2);
    *dst = make_float2(wr, wi);
}

// ---------------------------------------------------------------------------
// k_gemmA: G1[b,m1,n] = sum_m Wi[m,m1] (*) wd0[b,m,n]   (full complex)
// ---------------------------------------------------------------------------
__global__ __launch_bounds__(256) void k_gemmA(const float* __restrict__ Wi,
                                               float* __restrict__ ws) {
    const float* wd0 = ws + WS_MOD;
    float* G1        = ws + WS_G1;
    int nt = blockIdx.x, mt = blockIdx.y, b = blockIdx.z;
    __shared__ float As[16][128];
    __shared__ float Bs[16][128];
    int tid = threadIdx.x, tx = tid & 15, ty = tid >> 4;
    const float* Xb = wd0 + (size_t)b * 524288;
    int m1_0 = mt * 64, n0 = nt * 64;
    float cr[4][4] = {}, ci[4][4] = {};
    for (int k0 = 0; k0 < 512; k0 += 16) {
        for (int i = 0; i < 4; i++) {
            int flat = tid + i * 256;
            int col = flat & 63, kk = flat >> 6;
            const float2 sa = *(const float2*)(Wi + (((size_t)(k0 + kk) * 512) + m1_0 + col) * 2);
            As[kk][col * 2] = sa.x; As[kk][col * 2 + 1] = sa.y;
            const float2 sb = *(const float2*)(Xb + (((size_t)(k0 + kk) * 512) + n0 + col) * 2);
            Bs[kk][col * 2] = sb.x; Bs[kk][col * 2 + 1] = sb.y;
        }
        __syncthreads();
        for (int kk = 0; kk < 16; kk++) {
            float ar[4], ai[4], br[4], bi[4];
            for (int i = 0; i < 4; i++) { ar[i] = As[kk][(ty * 4 + i) * 2]; ai[i] = As[kk][(ty * 4 + i) * 2 + 1]; }
            for (int j = 0; j < 4; j++) { br[j] = Bs[kk][(tx * 4 + j) * 2]; bi[j] = Bs[kk][(tx * 4 + j) * 2 + 1]; }
            for (int i = 0; i < 4; i++)
                for (int j = 0; j < 4; j++) {
                    cr[i][j] += ar[i] * br[j] - ai[i] * bi[j];
                    ci[i][j] += ar[i] * bi[j] + ai[i] * br[j];
                }
        }
        __syncthreads();
    }
    float* Gb = G1 + (size_t)b * 524288;
    for (int i = 0; i < 4; i++) {
        float* dst = Gb + (((size_t)(m1_0 + ty * 4 + i) * 512) + n0 + tx * 4) * 2;
        for (int j = 0; j < 4; j++) { dst[j * 2] = cr[i][j]; dst[j * 2 + 1] = ci[i][j]; }
    }
}

// ---------------------------------------------------------------------------
// k_gemmB: out[b,m,n1] = CC + Re( sum_n G1[b,m,n] (*) (alpha*Wj[n,n1]) )
// ---------------------------------------------------------------------------
__global__ __launch_bounds__(256) void k_gemmB(const float* __restrict__ Wj,
                                               const float* __restrict__ ws,
                                               float* __restrict__ out) {
    const float* G1   = ws + WS_G1;
    const float* scal = ws + WS_SCAL;
    int nt = blockIdx.x, mt = blockIdx.y, b = blockIdx.z;
    __shared__ float As[64][34];   // [mm][kk*2+comp], padded row stride
    __shared__ float Bs[16][128];
    float al_r = scal[0], al_i = scal[1], CC = scal[2];
    int tid = threadIdx.x, tx = tid & 15, ty = tid >> 4;
    const float* Ab = G1 + (size_t)b * 524288;
    int m0 = mt * 64, n0 = nt * 64;
    float acc[4][4] = {};
    for (int k0 = 0; k0 < 512; k0 += 16) {
        for (int i = 0; i < 4; i++) {
            int flat = tid + i * 256;
            int kk = flat & 15, mm = flat >> 4;
            const float2 sa = *(const float2*)(Ab + (((size_t)(m0 + mm) * 512) + k0 + kk) * 2);
            As[mm][kk * 2] = sa.x; As[mm][kk * 2 + 1] = sa.y;
            int nn = flat & 63, kk2 = flat >> 6;
            const float2 sb = *(const float2*)(Wj + (((size_t)(k0 + kk2) * 512) + n0 + nn) * 2);
            Bs[kk2][nn * 2]     = al_r * sb.x - al_i * sb.y;
            Bs[kk2][nn * 2 + 1] = al_r * sb.y + al_i * sb.x;
        }
        __syncthreads();
        for (int kk = 0; kk < 16; kk++) {
            float a0[4], a1[4], b0[4], b1[4];
            for (int i = 0; i < 4; i++) { a0[i] = As[ty * 4 + i][kk * 2]; a1[i] = As[ty * 4 + i][kk * 2 + 1]; }
            for (int j = 0; j < 4; j++) { b0[j] = Bs[kk][(tx * 4 + j) * 2]; b1[j] = Bs[kk][(tx * 4 + j) * 2 + 1]; }
            for (int i = 0; i < 4; i++)
                for (int j = 0; j < 4; j++)
                    acc[i][j] += a0[i] * b0[j] - a1[i] * b1[j];
        }
        __syncthreads();
    }
    float* ob = out + (size_t)b * 262144;
    for (int i = 0; i < 4; i++) {
        float* dst = ob + (size_t)(m0 + ty * 4 + i) * 512 + n0 + tx * 4;
        for (int j = 0; j < 4; j++) dst[j] = acc[i][j] + CC;
    }
}

// ---------------------------------------------------------------------------
extern "C" void kernel_launch(void* const* d_in, const int* in_sizes, int n_in,
                              void* d_out, int out_size, void* d_ws, size_t ws_size,
                              hipStream_t stream) {
    const float* x    = (const float*)d_in[0];
    const float* Wi   = (const float*)d_in[1];
    const float* Wj   = (const float*)d_in[2];
    const float* base = (const float*)d_in[3];
    // d_in[4] translate_base, d_in[5] rotate_base: dead code in reference
    const float* td   = (const float*)d_in[6];
    const float* rd   = (const float*)d_in[7];
    const float* modi = (const float*)d_in[8];
    const float* modj = (const float*)d_in[9];
    const float* inv  = (const float*)d_in[10];
    const float* mt   = (const float*)d_in[11];
    float* ws  = (float*)d_ws;
    float* out = (float*)d_out;

    k_prep<<<1, 256, 0, stream>>>(x, mt, inv, td, rd, ws);
    k_mi<<<256, 256, 0, stream>>>(modi, ws);
    k_mj<<<256, 256, 0, stream>>>(modj, inv, ws);
    k_mod<<<dim3(8, 8, 8), 256, 0, stream>>>(ws);
    k_stats<<<1, 512, 0, stream>>>(ws);
    k_wd0<<<8192, 256, 0, stream>>>(base, ws);
    k_gemmA<<<dim3(8, 8, 8), 256, 0, stream>>>(Wi, ws);
    k_gemmB<<<dim3(8, 8, 8), 256, 0, stream>>>(Wj, ws, out);
}

// Round 2
// 157.567 us; speedup vs baseline: 2.9060x; 2.9060x over previous
//
#include <hip/hip_runtime.h>
#include <hip/hip_bf16.h>
#include <math.h>

// Shapes (fixed): B=8, C=16, R=16, M=N=512. K of both real GEMMs = 1024.
//
// Pipeline:
//   k_prep   : t=einsum, (d,e) rotation per (b,c), alpha=(-S0,-S1), CC
//   k_trans  : mode0 Wi -> A2 (bf16, [m1][2m+c]); mode1 Wj -> B5T (bf16,
//              [n1][2n+c] = (W'_r, -W'_i), W'=alpha*Wj); mode2 base -> baseT
//   k_mi/k_mj: rank-16 factors (fp32, same math as round 1 - verified)
//   k_modT   : modT[b][n][m] = sum_r mj(x)mi  + stats partials
//   k_stats  : mu, 1/std (ddof=1)
//   k_wd0    : wd0 = baseT*(1+[norm(mod_r),mod_i]) -> B2T bf16 expanded-transposed
//   k_gemm<1024,true> : G1x[b] = A2 . B2  (bf16 out, MFMA)   512x1024x1024
//   k_gemm<512,false> : out[b] = CC + G1x . B5               512x1024x512

#define WS_T       0
#define WS_DE      1024
#define WS_SCAL    1280
#define WS_STATS   1296
#define WS_PART    1536
#define WS_MIS     4096
#define WS_MJS     135168
#define WS_BASET   266240
#define WS_A2      790528
#define WS_B5T     1052672
#define WS_MODT    1314816
#define WS_G1X     1314816      // aliases MODT (modT dead before gemmA writes)
#define WS_B2T     5509120      // end: 9,703,424 floats (~37 MB)

typedef __attribute__((ext_vector_type(8))) short short8;
typedef __attribute__((ext_vector_type(4))) float f32x4;

__device__ __forceinline__ unsigned short f2bf(float f) {
    unsigned int u = __float_as_uint(f);
    u = (u + 0x7FFFu + ((u >> 16) & 1u)) >> 16;
    return (unsigned short)u;
}
__device__ __forceinline__ unsigned int pack2bf(float a, float b) {
    return (unsigned int)f2bf(a) | ((unsigned int)f2bf(b) << 16);
}
__device__ __forceinline__ void load_lds16(const unsigned int* g, unsigned short* l) {
    __builtin_amdgcn_global_load_lds((const __attribute__((address_space(1))) unsigned int*)g,
                                     (__attribute__((address_space(3))) unsigned int*)l, 16, 0, 0);
}

// ---------------------------------------------------------------------------
__global__ void k_prep(const float* __restrict__ x, const float* __restrict__ mt,
                       const float* __restrict__ inv, const float* __restrict__ td,
                       const float* __restrict__ rd, float* __restrict__ ws) {
    float* tbuf = ws + WS_T;
    float* de   = ws + WS_DE;
    float* scal = ws + WS_SCAL;
    int tid = threadIdx.x;
    for (int i = tid; i < 1024; i += 256) {
        int b = i >> 7, k = (i >> 5) & 3, l = i & 31;
        float s = 0.f;
        for (int c = 0; c < 16; c++) s += x[b * 16 + c] * mt[(k * 16 + c) * 32 + l];
        tbuf[i] = s;
    }
    __syncthreads();
    if (tid < 128) {
        int b = tid >> 4, c = tid & 15;
        float i0 = inv[2 * c], i1 = inv[2 * c + 1];
        float z0 = tbuf[(b * 4 + 1) * 32 + 2 * c], z1 = tbuf[(b * 4 + 1) * 32 + 2 * c + 1];
        de[tid * 2]     = i0 * z0 + i1 * z1;
        de[tid * 2 + 1] = i0 * z1 - i1 * z0;
    }
    if (tid == 0) {
        float S0 = 0.f, S1 = 0.f, CCv = 0.f;
        for (int c = 0; c < 16; c++) {
            float r0 = rd[2 * c], r1 = rd[2 * c + 1];
            float t0 = td[2 * c], t1 = td[2 * c + 1];
            S0 += r0; S1 += r1;
            CCv += t1 * r1 - t0 * r0;
        }
        scal[0] = -S0; scal[1] = -S1; scal[2] = CCv;
    }
}

// ---------------------------------------------------------------------------
// k_trans: 32x32 tiled transposes. mode0: Wi->A2, mode1: Wj->B5T (*alpha, -im),
// mode2: base->baseT (fp32)
__global__ void k_trans(const float* __restrict__ Wi, const float* __restrict__ Wj,
                        const float* __restrict__ base, float* __restrict__ ws) {
    __shared__ float2 tile[32][33];
    int mode = blockIdx.z;
    int bx = blockIdx.x, by = blockIdx.y;
    int tx = threadIdx.x & 31, ty = threadIdx.x >> 5;
    const float* src = (mode == 0) ? Wi : (mode == 1) ? Wj : base;
    for (int i = 0; i < 4; i++) {
        int rIn = by * 32 + ty + i * 8;    // m (or n)
        int cIn = bx * 32 + tx;            // m1 (or n1)
        tile[ty + i * 8][tx] = *(const float2*)(src + ((size_t)rIn * 512 + cIn) * 2);
    }
    __syncthreads();
    if (mode == 0) {
        unsigned int* A2u = (unsigned int*)(ws + WS_A2);
        for (int i = 0; i < 4; i++) {
            int rOut = bx * 32 + ty + i * 8;    // m1
            int cOut = by * 32 + tx;            // m
            float2 v = tile[tx][ty + i * 8];
            A2u[(size_t)rOut * 512 + cOut] = pack2bf(v.x, v.y);
        }
    } else if (mode == 1) {
        const float* scal = ws + WS_SCAL;
        float ar = scal[0], ai = scal[1];
        unsigned int* B5u = (unsigned int*)(ws + WS_B5T);
        for (int i = 0; i < 4; i++) {
            int rOut = bx * 32 + ty + i * 8;    // n1
            int cOut = by * 32 + tx;            // n
            float2 v = tile[tx][ty + i * 8];
            float wr = ar * v.x - ai * v.y;
            float wi = ar * v.y + ai * v.x;
            B5u[(size_t)rOut * 512 + cOut] = pack2bf(wr, -wi);
        }
    } else {
        float* baseT = ws + WS_BASET;
        for (int i = 0; i < 4; i++) {
            int rOut = bx * 32 + ty + i * 8;    // n
            int cOut = by * 32 + tx;            // m
            *(float2*)(baseT + ((size_t)rOut * 512 + cOut) * 2) = tile[tx][ty + i * 8];
        }
    }
}

// ---------------------------------------------------------------------------
__global__ void k_mi(const float* __restrict__ mod_i, float* __restrict__ ws) {
    const float* tbuf = ws + WS_T;
    const float* de   = ws + WS_DE;
    float* mi_s       = ws + WS_MIS;
    int id = blockIdx.x * 256 + threadIdx.x;
    int b = id >> 13, rm = id & 8191;
    int r = rm >> 9, m = rm & 511;
    float acc0 = 0.f, acc1 = 0.f;
    for (int c = 0; c < 16; c++) {
        const float* p = mod_i + (((size_t)(c * 16 + r) * 512) + m) * 2;
        float t00 = tbuf[(b * 4 + 0) * 32 + 2 * c];
        float t01 = tbuf[(b * 4 + 0) * 32 + 2 * c + 1];
        float d = de[(b * 16 + c) * 2], e = de[(b * 16 + c) * 2 + 1];
        float A0 = p[0] + t00, A1 = p[1] + t01;
        acc0 += d * A0 - e * A1;
        acc1 += e * A0 + d * A1;
    }
    float* dst = mi_s + ((size_t)b * 8192 + rm) * 2;
    dst[0] = acc0; dst[1] = acc1;
}

__global__ void k_mj(const float* __restrict__ mod_j, const float* __restrict__ inv,
                     float* __restrict__ ws) {
    const float* tbuf = ws + WS_T;
    float* mj_s       = ws + WS_MJS;
    int id = blockIdx.x * 256 + threadIdx.x;
    int b = id >> 13, rn = id & 8191;
    int r = rn >> 9, n = rn & 511;
    float acc0 = 0.f, acc1 = 0.f;
    for (int c = 0; c < 16; c++) {
        const float* p = mod_j + (((size_t)(c * 16 + r) * 512) + n) * 2;
        float t20 = tbuf[(b * 4 + 2) * 32 + 2 * c];
        float t21 = tbuf[(b * 4 + 2) * 32 + 2 * c + 1];
        float z0  = tbuf[(b * 4 + 3) * 32 + 2 * c];
        float z1  = tbuf[(b * 4 + 3) * 32 + 2 * c + 1];
        float A0 = p[0] + t20, A1 = p[1] + t21;
        float w0 = -z0 * A0 + z1 * A1;
        float w1 =  z1 * A0 + z0 * A1;
        float i0 = inv[2 * c], i1 = inv[2 * c + 1];
        float den = w0 * w0 + w1 * w1;
        acc0 += (i0 * w0 + i1 * w1) / den;
        acc1 += (i0 * w1 - i1 * w0) / den;
    }
    float* dst = mj_s + ((size_t)b * 8192 + rn) * 2;
    dst[0] = acc0; dst[1] = acc1;
}

// ---------------------------------------------------------------------------
// k_modT: modT[b][n][m] = sum_r mj_s[r][n] (x) mi_s[r][m]  (complex) + stats
__global__ __launch_bounds__(256) void k_modT(float* __restrict__ ws) {
    const float* mi_s = ws + WS_MIS;
    const float* mj_s = ws + WS_MJS;
    float* modT       = ws + WS_MODT;
    float* partials   = ws + WS_PART;
    int mt = blockIdx.x, nt = blockIdx.y, b = blockIdx.z;
    __shared__ float Ns[16][128];
    __shared__ float Ms[16][128];
    __shared__ float red[512];
    int tid = threadIdx.x, tx = tid & 15, ty = tid >> 4;
    const float* Nb = mj_s + (size_t)b * 16384;
    const float* Mb = mi_s + (size_t)b * 16384;
    int n0 = nt * 64, m0 = mt * 64;
    for (int i = 0; i < 4; i++) {
        int flat = tid + i * 256;
        int col = flat & 63, r = flat >> 6;
        float2 sa = *(const float2*)(Nb + ((size_t)r * 512 + n0 + col) * 2);
        Ns[r][col * 2] = sa.x; Ns[r][col * 2 + 1] = sa.y;
        float2 sb = *(const float2*)(Mb + ((size_t)r * 512 + m0 + col) * 2);
        Ms[r][col * 2] = sb.x; Ms[r][col * 2 + 1] = sb.y;
    }
    __syncthreads();
    float cr[4][4] = {}, ci[4][4] = {};
    for (int r = 0; r < 16; r++) {
        float nr[4], ni[4], mr[4], mi_[4];
        for (int i = 0; i < 4; i++) { nr[i] = Ns[r][(ty * 4 + i) * 2]; ni[i] = Ns[r][(ty * 4 + i) * 2 + 1]; }
        for (int j = 0; j < 4; j++) { mr[j] = Ms[r][(tx * 4 + j) * 2]; mi_[j] = Ms[r][(tx * 4 + j) * 2 + 1]; }
        for (int i = 0; i < 4; i++)
            for (int j = 0; j < 4; j++) {
                cr[i][j] += nr[i] * mr[j] - ni[i] * mi_[j];
                ci[i][j] += nr[i] * mi_[j] + ni[i] * mr[j];
            }
    }
    float s1 = 0.f, s2 = 0.f;
    float* ob = modT + (size_t)b * 524288;
    for (int i = 0; i < 4; i++) {
        float* dst = ob + ((size_t)(n0 + ty * 4 + i) * 512 + m0 + tx * 4) * 2;
        for (int j = 0; j < 4; j++) {
            dst[j * 2] = cr[i][j]; dst[j * 2 + 1] = ci[i][j];
            s1 += cr[i][j]; s2 += cr[i][j] * cr[i][j];
        }
    }
    red[tid] = s1; red[256 + tid] = s2;
    __syncthreads();
    for (int s = 128; s > 0; s >>= 1) {
        if (tid < s) { red[tid] += red[tid + s]; red[256 + tid] += red[256 + tid + s]; }
        __syncthreads();
    }
    if (tid == 0) {
        float* dst = partials + ((size_t)b * 64 + nt * 8 + mt) * 2;
        dst[0] = red[0]; dst[1] = red[256];
    }
}

__global__ void k_stats(float* __restrict__ ws) {
    const float* partials = ws + WS_PART;
    float* stats          = ws + WS_STATS;
    __shared__ float s1[512], s2[512];
    int tid = threadIdx.x;
    int b = tid >> 6, i = tid & 63;
    s1[tid] = partials[(b * 64 + i) * 2];
    s2[tid] = partials[(b * 64 + i) * 2 + 1];
    __syncthreads();
    for (int s = 32; s > 0; s >>= 1) {
        if (i < s) { s1[tid] += s1[tid + s]; s2[tid] += s2[tid + s]; }
        __syncthreads();
    }
    if (i == 0) {
        double MN = 262144.0;
        double mu = (double)s1[tid] / MN;
        double var = ((double)s2[tid] - MN * mu * mu) / (MN - 1.0);
        if (var < 1e-30) var = 1e-30;
        stats[b * 2] = (float)mu;
        stats[b * 2 + 1] = (float)(1.0 / sqrt(var));
    }
}

// ---------------------------------------------------------------------------
// k_wd0: B2T[b][2n+0][2m..] = (wr,-wi) ; [2n+1][2m..] = (wi,wr)  (bf16 pairs)
__global__ void k_wd0(float* __restrict__ ws) {
    const float* stats = ws + WS_STATS;
    const float* modT  = ws + WS_MODT;
    const float* baseT = ws + WS_BASET;
    unsigned int* B2T  = (unsigned int*)(ws + WS_B2T);
    int id = blockIdx.x * 256 + threadIdx.x;     // 2,097,152
    int b = id >> 18, nm = id & 262143;
    int n = nm >> 9, m = nm & 511;
    float mu = stats[b * 2], rstd = stats[b * 2 + 1];
    float2 mv = *(const float2*)(modT + ((size_t)b * 262144 + nm) * 2);
    float2 bs = *(const float2*)(baseT + (size_t)nm * 2);
    float wr = bs.x * (1.f + (mv.x - mu) * rstd);
    float wi = bs.y * (1.f + mv.y);
    unsigned int* Bb = B2T + (size_t)b * 524288;
    Bb[(size_t)(2 * n) * 512 + m]     = pack2bf(wr, -wi);
    Bb[(size_t)(2 * n + 1) * 512 + m] = pack2bf(wi, wr);
}

// ---------------------------------------------------------------------------
// MFMA GEMM: C[M x NGL] = A[M x 1024] . BT[NGL x 1024]^T, bf16 in, 128x128 tile
// XOR-swizzled LDS (chunk c stores global chunk c^(r&7)) keeps global_load_lds
// lane-linear while making frag ds_read_b128 ~2-way (free) instead of 16-way.
template <int NGL, bool OUT_BF16>
__global__ __launch_bounds__(256) void k_gemm(const unsigned short* __restrict__ Aall,
                                              const unsigned short* __restrict__ BTall,
                                              void* __restrict__ Call,
                                              const float* __restrict__ scal,
                                              size_t a_bs, size_t bt_bs, size_t c_bs) {
    constexpr int K = 1024;
    __shared__ __align__(16) unsigned short As[128 * 64];
    __shared__ __align__(16) unsigned short Bs[128 * 64];
    const int tid = threadIdx.x;
    const int b = blockIdx.z;
    const unsigned short* A  = Aall  + (size_t)b * a_bs;
    const unsigned short* BT = BTall + (size_t)b * bt_bs;
    const int mBase = blockIdx.y * 128;
    const int nBase = blockIdx.x * 128;
    const int wave = tid >> 6, lane = tid & 63;
    const int wm = wave >> 1, wn = wave & 1;
    const int l15 = lane & 15, q = lane >> 4;

    f32x4 acc[4][4];
    for (int i = 0; i < 4; i++)
        for (int j = 0; j < 4; j++) acc[i][j] = (f32x4)0.f;

    const int flat0 = tid;
    for (int k0 = 0; k0 < K; k0 += 64) {
#pragma unroll
        for (int p = 0; p < 4; p++) {
            int flat = flat0 + p * 256;
            int r = flat >> 3, c = flat & 7;
            int gc = ((c ^ (r & 7)) << 3);
            load_lds16((const unsigned int*)(A + (size_t)(mBase + r) * K + k0 + gc),
                       &As[flat << 3]);
            load_lds16((const unsigned int*)(BT + (size_t)(nBase + r) * K + k0 + gc),
                       &Bs[flat << 3]);
        }
        __syncthreads();
#pragma unroll
        for (int ks = 0; ks < 2; ks++) {
            short8 af[4], bfr[4];
#pragma unroll
            for (int t = 0; t < 4; t++) {
                int ra = wm * 64 + t * 16 + l15;
                int ja = (ks * 4 + q) ^ (ra & 7);
                af[t] = *(const short8*)&As[ra * 64 + ja * 8];
                int rb = wn * 64 + t * 16 + l15;
                int jb = (ks * 4 + q) ^ (rb & 7);
                bfr[t] = *(const short8*)&Bs[rb * 64 + jb * 8];
            }
#pragma unroll
            for (int i = 0; i < 4; i++)
#pragma unroll
                for (int j = 0; j < 4; j++)
                    acc[i][j] = __builtin_amdgcn_mfma_f32_16x16x32_bf16(af[i], bfr[j], acc[i][j], 0, 0, 0);
        }
        __syncthreads();
    }

    if constexpr (OUT_BF16) {
        __shared__ __align__(16) unsigned short Cs[128 * 132];
#pragma unroll
        for (int i = 0; i < 4; i++) {
            int row0 = wm * 64 + i * 16 + q * 4;
#pragma unroll
            for (int j = 0; j < 4; j++) {
                int col = wn * 64 + j * 16 + l15;
#pragma unroll
                for (int r = 0; r < 4; r++)
                    Cs[(row0 + r) * 132 + col] = f2bf(acc[i][j][r]);
            }
        }
        __syncthreads();
        unsigned short* C = (unsigned short*)Call + (size_t)b * c_bs;
#pragma unroll
        for (int p = 0; p < 8; p++) {
            int flat = tid + p * 256;
            int r = flat >> 4, c = flat & 15;
            short8 v = *(const short8*)&Cs[r * 132 + c * 8];
            *(short8*)(C + (size_t)(mBase + r) * NGL + nBase + c * 8) = v;
        }
    } else {
        float CC = scal[2];
        float* C = (float*)Call + (size_t)b * c_bs;
#pragma unroll
        for (int i = 0; i < 4; i++) {
            int row0 = wm * 64 + i * 16 + q * 4;
#pragma unroll
            for (int j = 0; j < 4; j++) {
                int col = wn * 64 + j * 16 + l15;
#pragma unroll
                for (int r = 0; r < 4; r++)
                    C[(size_t)(mBase + row0 + r) * NGL + nBase + col] = acc[i][j][r] + CC;
            }
        }
    }
}

// ---------------------------------------------------------------------------
extern "C" void kernel_launch(void* const* d_in, const int* in_sizes, int n_in,
                              void* d_out, int out_size, void* d_ws, size_t ws_size,
                              hipStream_t stream) {
    const float* x    = (const float*)d_in[0];
    const float* Wi   = (const float*)d_in[1];
    const float* Wj   = (const float*)d_in[2];
    const float* base = (const float*)d_in[3];
    const float* td   = (const float*)d_in[6];
    const float* rd   = (const float*)d_in[7];
    const float* modi = (const float*)d_in[8];
    const float* modj = (const float*)d_in[9];
    const float* inv  = (const float*)d_in[10];
    const float* mt   = (const float*)d_in[11];
    float* ws  = (float*)d_ws;
    float* out = (float*)d_out;

    unsigned short* A2  = (unsigned short*)(ws + WS_A2);
    unsigned short* B5T = (unsigned short*)(ws + WS_B5T);
    unsigned short* B2T = (unsigned short*)(ws + WS_B2T);
    unsigned short* G1X = (unsigned short*)(ws + WS_G1X);
    const float* scal   = ws + WS_SCAL;

    k_prep<<<1, 256, 0, stream>>>(x, mt, inv, td, rd, ws);
    k_trans<<<dim3(16, 16, 3), 256, 0, stream>>>(Wi, Wj, base, ws);
    k_mi<<<256, 256, 0, stream>>>(modi, ws);
    k_mj<<<256, 256, 0, stream>>>(modj, inv, ws);
    k_modT<<<dim3(8, 8, 8), 256, 0, stream>>>(ws);
    k_stats<<<1, 512, 0, stream>>>(ws);
    k_wd0<<<8192, 256, 0, stream>>>(ws);
    k_gemm<1024, true><<<dim3(8, 4, 8), 256, 0, stream>>>(
        A2, B2T, (void*)G1X, scal, (size_t)0, (size_t)1048576, (size_t)524288);
    k_gemm<512, false><<<dim3(4, 4, 8), 256, 0, stream>>>(
        G1X, B5T, (void*)out, scal, (size_t)524288, (size_t)0, (size_t)262144);
}